// Round 15
// baseline (65.368 us; speedup 1.0000x reference)
//
#include <hip/hip_runtime.h>
#include <math.h>

#define J   29
#define CH  3
#define JC  87            // J*CH
#define E0  56
#define B   256
#define T   1024
#define FRAMES (B*T)      // 262144
#define FPC 64            // frames per chunk (= lanes)
#define CPB 8             // chunks per block
#define NBLK (FRAMES/(FPC*CPB)) // 512
#define CHUNK_F4 1392     // float4s per chunk (22272 B)
#define BPB (T/(FPC*CPB)) // 2 partials per batch
#define SLOTS 4           // static slots per row (overflow beyond)
#define WAVES 8
#define RPW 4             // rows per wave (rows 29..31 padding)
#define OVCAP 64          // per-wave overflow capacity

// ---- fused main: inline prep + depth-2 reg prefetch + packed gather --------
__global__ __launch_bounds__(512, 4)
void gcn_main(const float* __restrict__ x,
              const int*   __restrict__ ei,
              const float* __restrict__ Wp,
              const float* __restrict__ bp,
              float* __restrict__ partials) {
    __shared__ float4 xs4[CHUNK_F4];        // 22272 B packed [64][87]
    __shared__ int2   s_ov[WAVES * OVCAP];  // per-wave overflow lists

    int tid  = threadIdx.x;
    int lane = tid & 63;
    int wv   = tid >> 6;
    int rowbase = __builtin_amdgcn_readfirstlane(wv * RPW);  // 0,4,...,28

    const float4* src4 = (const float4*)x + (size_t)blockIdx.x * (CPB * CHUNK_F4);
    int i2 = 1024 + tid; if (i2 > CHUNK_F4 - 1) i2 = CHUNK_F4 - 1;

    // ---- fire chunk 0 AND chunk 1 prefetches first (depth-2 pipe fill) ----
    float4 pfA0 = src4[tid], pfA1 = src4[512 + tid], pfA2 = src4[i2];
    const float4* s1 = src4 + CHUNK_F4;
    float4 pfB0 = s1[tid],  pfB1 = s1[512 + tid],  pfB2 = s1[i2];

    // ---- inline prep (R10-proven ballot build), overlapped with pf flight --
    float dinv = 0.f;
    if (lane < J) {
        int d = 1;
        for (int e = 0; e < E0; ++e) d += (ei[E0 + e] == lane) ? 1 : 0;
        dinv = rsqrtf((float)d);
    }
    int   prx[RPW][SLOTS];
    float prv[RPW][SLOTS];
    int ovn = 0;                                        // wave-uniform
#pragma unroll
    for (int R = 0; R < RPW; ++R) {
        int j = rowbase + R;
        float mv = 0.f;
        if (lane < J && j < J) {
            int cnt = 0;
            for (int e = 0; e < E0; ++e)
                cnt += (ei[e] == lane && ei[E0 + e] == j) ? 1 : 0;
            float dj = __shfl(dinv, j);
            mv = (float)cnt * dinv * dj;
            if (lane == j) mv += dinv * dinv;
        }
        unsigned long long mask = __ballot(mv != 0.f);  // wave-uniform
#pragma unroll
        for (int sl = 0; sl < SLOTS; ++sl) {
            int pos = 0; float v = 0.f;
            if (mask) {
                pos = __ffsll(mask) - 1;
                v = __shfl(mv, pos);
                mask &= mask - 1;
            }
            prx[R][sl] = pos * 12;                      // packed col offset
            prv[R][sl] = v;
        }
        while (mask) {                                  // rare overflow
            int pos = __ffsll(mask) - 1;
            mask &= mask - 1;
            float v = __shfl(mv, pos);
            if (lane == 0) {
                int2 pr; pr.x = (j << 16) | (pos * 12); pr.y = __float_as_int(v);
                s_ov[wv * OVCAP + ovn] = pr;
            }
            ++ovn;
        }
    }
    float sW[9], sb[CH];
#pragma unroll
    for (int i = 0; i < 9; ++i) sW[i] = Wp[i];
#pragma unroll
    for (int i = 0; i < CH; ++i) sb[i] = bp[i];

    float acc[RPW][CH];
#pragma unroll
    for (int r = 0; r < RPW; ++r)
#pragma unroll
        for (int c = 0; c < CH; ++c) acc[r][c] = 0.f;

#define COMPUTE_CHUNK                                                         \
    {                                                                         \
        const char* xf = (const char*)xs4 + lane * 348;                       \
        float y[RPW][CH];                                                     \
        _Pragma("unroll")                                                     \
        for (int R = 0; R < RPW; ++R) {                                       \
            float a0 = 0.f, a1 = 0.f, a2 = 0.f;                               \
            _Pragma("unroll")                                                 \
            for (int sl = 0; sl < SLOTS; ++sl) {                              \
                float v = prv[R][sl];                                         \
                const float* q = (const float*)(xf + prx[R][sl]);             \
                a0 += v * q[0]; a1 += v * q[1]; a2 += v * q[2];               \
            }                                                                 \
            y[R][0] = a0; y[R][1] = a1; y[R][2] = a2;                         \
        }                                                                     \
        for (int e = 0; e < ovn; ++e) {                                       \
            int2 pr = s_ov[wv * OVCAP + e];                                   \
            int row = pr.x >> 16; int off = pr.x & 0xFFFF;                    \
            float v = __int_as_float(pr.y);                                   \
            const float* q = (const float*)(xf + off);                        \
            float d0 = v * q[0], d1 = v * q[1], d2 = v * q[2];                \
            _Pragma("unroll")                                                 \
            for (int R = 0; R < RPW; ++R)                                     \
                if (row == rowbase + R) { y[R][0] += d0; y[R][1] += d1; y[R][2] += d2; } \
        }                                                                     \
        _Pragma("unroll")                                                     \
        for (int R = 0; R < RPW; ++R)                                         \
            _Pragma("unroll")                                                 \
            for (int ch = 0; ch < CH; ++ch) {                                 \
                float t = y[R][0] * sW[0 * CH + ch]                           \
                        + y[R][1] * sW[1 * CH + ch]                           \
                        + y[R][2] * sW[2 * CH + ch]                           \
                        + sb[ch];                                             \
                acc[R][ch] += fmaxf(t, 0.f);                                  \
            }                                                                 \
    }

    // ---- main loop: 2 chunks in flight, alternating named reg sets --------
#pragma unroll
    for (int c = 0; c < CPB; c += 2) {
        __syncthreads();                    // xs free; (c=0) prep LDS visible
        xs4[tid] = pfA0; xs4[512 + tid] = pfA1; xs4[i2] = pfA2;
        __syncthreads();                    // chunk c visible
        if (c + 2 < CPB) {
            const float4* sn = src4 + (c + 2) * CHUNK_F4;
            pfA0 = sn[tid]; pfA1 = sn[512 + tid]; pfA2 = sn[i2];
        }
        COMPUTE_CHUNK;                      // chunk c

        __syncthreads();
        xs4[tid] = pfB0; xs4[512 + tid] = pfB1; xs4[i2] = pfB2;
        __syncthreads();                    // chunk c+1 visible
        if (c + 3 < CPB) {
            const float4* sn = src4 + (c + 3) * CHUNK_F4;
            pfB0 = sn[tid]; pfB1 = sn[512 + tid]; pfB2 = sn[i2];
        }
        COMPUTE_CHUNK;                      // chunk c+1
    }

    // ---- epilogue: transposed LDS write + 87-thread column reduce ----------
    __syncthreads();
    float* red = (float*)xs4;     // [64][87]
#pragma unroll
    for (int R = 0; R < RPW; ++R) {
        int j = rowbase + R;
        if (j < J) {
#pragma unroll
            for (int ch = 0; ch < CH; ++ch)
                red[lane * JC + j * CH + ch] = acc[R][ch];
        }
    }
    __syncthreads();
    if (tid < JC) {
        float a = 0.f;
#pragma unroll
        for (int L = 0; L < FPC; ++L) a += red[L * JC + tid];
        partials[(size_t)blockIdx.x * JC + tid] = a;
    }
}

// ---- finalize: mean over frames + fc + sigmoid ------------------------------
__global__ void finalize_kernel(const float* __restrict__ partials,
                                const float* __restrict__ fcW,
                                const float* __restrict__ fcb,
                                float* __restrict__ out) {
    __shared__ float h[JC];
    int b = blockIdx.x, tid = threadIdx.x;
    if (tid < JC) {
        float a = 0.f;
#pragma unroll
        for (int p = 0; p < BPB; ++p)
            a += partials[(size_t)(b * BPB + p) * JC + tid];
        a *= (1.0f / (float)T);
        h[tid] = a;
        out[(size_t)b * JC + tid] = a;
    }
    __syncthreads();
    if (tid < 2) {
        float a = fcb[tid];
        for (int r = 0; r < JC; ++r) a += h[r] * fcW[r * 2 + tid];
        out[(size_t)B * JC + b * 2 + tid] = 1.0f / (1.0f + expf(-a));
    }
}

extern "C" void kernel_launch(void* const* d_in, const int* in_sizes, int n_in,
                              void* d_out, int out_size, void* d_ws, size_t ws_size,
                              hipStream_t stream) {
    const float* x   = (const float*)d_in[0];
    const int*   ei  = (const int*)d_in[1];
    const float* W   = (const float*)d_in[4];
    const float* bb  = (const float*)d_in[5];
    const float* fcW = (const float*)d_in[6];
    const float* fcb = (const float*)d_in[7];

    float* partials = (float*)d_ws;          // 512*87 floats

    gcn_main<<<NBLK, WAVES * 64, 0, stream>>>(x, ei, W, bb, partials);
    finalize_kernel<<<B, 128, 0, stream>>>(partials, fcW, fcb, (float*)d_out);
}